// Round 1
// baseline (433.706 us; speedup 1.0000x reference)
//
#include <hip/hip_runtime.h>
#include <stdint.h>

using bf16 = __bf16;
typedef __bf16 bf16x8 __attribute__((ext_vector_type(8)));
typedef __bf16 bf16x4 __attribute__((ext_vector_type(4)));
typedef float f32x4 __attribute__((ext_vector_type(4)));

#define H_ 16
#define KV_ 4
#define D_ 128
#define WIN_ 1024
#define B_ 2
#define S_ 2048
#define E_ 2048
#define HD_ 2048
#define NQKV_ 3072

// async global->LDS, 16B per lane. LDS dest must be wave-uniform-base + lane*16.
__device__ __forceinline__ void gld_lds16(const void* gptr, void* lptr) {
    __builtin_amdgcn_global_load_lds(
        (__attribute__((address_space(1))) void*)(uintptr_t)gptr,
        (__attribute__((address_space(3))) void*)(uintptr_t)lptr, 16, 0, 0);
}

// ---------------- fp32 -> bf16 conversion ----------------
__global__ __launch_bounds__(256) void cvt_f32_bf16(const float* __restrict__ src,
                                                    bf16* __restrict__ dst, int n) {
    int i = (blockIdx.x * 256 + threadIdx.x) * 4;
    if (i >= n) return;
    const float4 v = *(const float4*)(src + i);
    bf16x4 o = {(bf16)v.x, (bf16)v.y, (bf16)v.z, (bf16)v.w};
    *(bf16x4*)(dst + i) = o;
}

// ---------------- GEMM: C[m,n] = sum_k A[m,k] * W[n,k]  (W row-major (N,K)) ----------------
// 128x128 tile, BK=32, 4 waves each 64x64, 16x16x32 bf16 MFMA.
template <typename OutT>
__global__ __launch_bounds__(256) void gemm_bt(const bf16* __restrict__ A,
                                               const bf16* __restrict__ W,
                                               OutT* __restrict__ C, int K, int ldc) {
    __shared__ alignas(16) bf16 As[128 * 32];
    __shared__ alignas(16) bf16 Bs[128 * 32];
    const int t = threadIdx.x;
    const int lane = t & 63;
    const int wave = t >> 6;
    const int l15 = lane & 15;
    const int quad = lane >> 4;
    const int wm = (wave & 1) * 64;
    const int wn = (wave >> 1) * 64;
    const int m0 = blockIdx.x * 128;
    const int n0 = blockIdx.y * 128;

    f32x4 acc[4][4] = {};

    const int sr = t >> 2;       // 0..63
    const int sc = (t & 3) * 8;  // 0,8,16,24
    const bf16* Ap = A + (size_t)(m0 + sr) * K + sc;
    const bf16* Wp = W + (size_t)(n0 + sr) * K + sc;
    bf16* As0 = &As[t * 8];
    bf16* As1 = &As[64 * 32 + t * 8];
    bf16* Bs0 = &Bs[t * 8];
    bf16* Bs1 = &Bs[64 * 32 + t * 8];
    const size_t rowskip = (size_t)64 * K;

    for (int k0 = 0; k0 < K; k0 += 32) {
        gld_lds16(Ap + k0, As0);
        gld_lds16(Ap + k0 + rowskip, As1);
        gld_lds16(Wp + k0, Bs0);
        gld_lds16(Wp + k0 + rowskip, Bs1);
        __syncthreads();
        bf16x8 af[4], bfr[4];
#pragma unroll
        for (int i = 0; i < 4; ++i) {
            af[i] = *(const bf16x8*)&As[(wm + i * 16 + l15) * 32 + quad * 8];
            bfr[i] = *(const bf16x8*)&Bs[(wn + i * 16 + l15) * 32 + quad * 8];
        }
#pragma unroll
        for (int i = 0; i < 4; ++i)
#pragma unroll
            for (int j = 0; j < 4; ++j)
                acc[i][j] =
                    __builtin_amdgcn_mfma_f32_16x16x32_bf16(af[i], bfr[j], acc[i][j], 0, 0, 0);
        __syncthreads();
    }
    // epilogue: D row = quad*4+reg, col = lane&15 (verified gfx950 C/D layout)
#pragma unroll
    for (int i = 0; i < 4; ++i) {
        const int row = m0 + wm + i * 16 + quad * 4;
#pragma unroll
        for (int j = 0; j < 4; ++j) {
            const int col = n0 + wn + j * 16 + l15;
#pragma unroll
            for (int r = 0; r < 4; ++r) C[(size_t)(row + r) * ldc + col] = (OutT)acc[i][j][r];
        }
    }
}

// ---------------- RoPE + RMSNorm (+transpose) ----------------
// qkv: (B*S, 3072) bf16 raw projections. One wave per (b,s,unit) vector of 128.
// units: j<16 -> q head j ; 16..19 -> k head j-16 ; 20..23 -> v head j-20 (transpose only)
__global__ __launch_bounds__(256) void rope_norm(const bf16* __restrict__ qkv,
                                                 const float* __restrict__ cosp,
                                                 const float* __restrict__ sinp,
                                                 bf16* __restrict__ qn, bf16* __restrict__ kn,
                                                 bf16* __restrict__ vt) {
    const int unit = blockIdx.x * 4 + (threadIdx.x >> 6);
    const int lane = threadIdx.x & 63;
    const int b = unit / (S_ * 24);
    const int rem = unit - b * (S_ * 24);
    const int s = rem / 24;
    const int j = rem - s * 24;
    const size_t rowbase = (size_t)(b * S_ + s) * NQKV_;
    const float eps = 1.1920929e-7f;  // finfo(float32).eps

    if (j < 20) {
        const bf16* src = qkv + rowbase + ((j < 16) ? (j * 128) : (2048 + (j - 16) * 128));
        float x1 = (float)src[lane];
        float x2 = (float)src[lane + 64];
        float c = cosp[s * 64 + lane];
        float sn = sinp[s * 64 + lane];
        float y1 = x1 * c + x2 * sn;
        float y2 = -x1 * sn + x2 * c;
        float ss = y1 * y1 + y2 * y2;
#pragma unroll
        for (int off = 1; off < 64; off <<= 1) ss += __shfl_xor(ss, off, 64);
        float r = rsqrtf(ss * (1.0f / 128.0f) + eps);
        if (j < 16) {
            r *= 0.08838834764831845f;  // fold D^-0.5 into q
            bf16* dst = qn + (size_t)((b * H_ + j) * S_ + s) * 128;
            dst[lane] = (bf16)(y1 * r);
            dst[lane + 64] = (bf16)(y2 * r);
        } else {
            bf16* dst = kn + (size_t)((b * KV_ + (j - 16)) * S_ + s) * 128;
            dst[lane] = (bf16)(y1 * r);
            dst[lane + 64] = (bf16)(y2 * r);
        }
    } else {
        const int jv = j - 20;
        const bf16* src = qkv + rowbase + 2560 + jv * 128;
        bf16* dst = vt + (size_t)(b * KV_ + jv) * 128 * S_ + s;
        dst[(size_t)lane * S_] = src[lane];
        dst[(size_t)(lane + 64) * S_] = src[lane + 64];
    }
}

// ---------------- flash attention, sliding window ----------------
// Qn: (B,H,S,D) bf16 (scale folded). Kn: (B,KV,S,D). Vt: (B,KV,D,S). Out: (B,S,H*D) bf16.
// block = (qtile of 64, h, b); 4 waves x 16 q-rows; 32-key tiles.
__global__ __launch_bounds__(256) void attn_fwd(const bf16* __restrict__ Qn,
                                                const bf16* __restrict__ Kn,
                                                const bf16* __restrict__ Vt,
                                                bf16* __restrict__ Out) {
    __shared__ alignas(16) bf16 Ks[32 * 128];
    __shared__ alignas(16) bf16 Vs[128 * 32];
    __shared__ alignas(16) bf16 Ps[4 * 16 * 32];

    const int t = threadIdx.x;
    const int lane = t & 63;
    const int wave = t >> 6;
    const int l15 = lane & 15;
    const int quad = lane >> 4;
    const int qb0 = blockIdx.x * 64;
    const int h = blockIdx.y;
    const int b = blockIdx.z;
    const int hk = h >> 2;  // GQA: rep=4
    const int qw0 = qb0 + wave * 16;

    // Q fragments: A-operand layout A[m=lane&15][k=quad*8+j]
    const bf16* qbase = Qn + ((size_t)((b * H_ + h) * S_) + qw0 + l15) * 128;
    bf16x8 qf[4];
#pragma unroll
    for (int c = 0; c < 4; ++c) qf[c] = *(const bf16x8*)(qbase + c * 32 + quad * 8);

    f32x4 o[8] = {};
    float mrow[4], lrow[4];
#pragma unroll
    for (int r = 0; r < 4; ++r) {
        mrow[r] = -1e30f;
        lrow[r] = 0.0f;
    }

    const bf16* kroot = Kn + (size_t)((b * KV_ + hk) * S_) * 128;
    const bf16* vroot = Vt + (size_t)((b * KV_ + hk) * 128) * S_;

    int lo = qb0 - (WIN_ - 1);
    if (lo < 0) lo = 0;
    const int kb_start = lo & ~31;
    const int kb_end = qb0 + 64;

    const int skr = t >> 4;         // K stage row 0..15
    const int skc = (t & 15) * 8;   // K stage col
    const int svr = t >> 2;         // V stage row (d) 0..63
    const int svc = (t & 3) * 8;    // V stage col

    for (int kb = kb_start; kb < kb_end; kb += 32) {
        gld_lds16(kroot + (size_t)(kb + skr) * 128 + skc, &Ks[t * 8]);
        gld_lds16(kroot + (size_t)(kb + skr + 16) * 128 + skc, &Ks[16 * 128 + t * 8]);
        gld_lds16(vroot + (size_t)svr * S_ + kb + svc, &Vs[t * 8]);
        gld_lds16(vroot + (size_t)(svr + 64) * S_ + kb + svc, &Vs[64 * 32 + t * 8]);
        __syncthreads();

        // S = Q K^T : two 16x16 column-halves, accumulate over 4 d-chunks of 32
        f32x4 sacc[2] = {};
#pragma unroll
        for (int nh = 0; nh < 2; ++nh) {
#pragma unroll
            for (int c = 0; c < 4; ++c) {
                bf16x8 kf = *(const bf16x8*)&Ks[(nh * 16 + l15) * 128 + c * 32 + quad * 8];
                sacc[nh] = __builtin_amdgcn_mfma_f32_16x16x32_bf16(qf[c], kf, sacc[nh], 0, 0, 0);
            }
        }

        // online softmax (rows live in quad-groups: row = quad*4+r, col = lane&15)
        float p0[4], p1[4], alpha[4];
#pragma unroll
        for (int r = 0; r < 4; ++r) {
            const int qi = qw0 + quad * 4 + r;
            const int kj0 = kb + l15;
            const int kj1 = kb + 16 + l15;
            float s0 = ((kj0 <= qi) && (qi - kj0 < WIN_)) ? sacc[0][r] : -1e30f;
            float s1 = ((kj1 <= qi) && (qi - kj1 < WIN_)) ? sacc[1][r] : -1e30f;
            float mx = fmaxf(s0, s1);
#pragma unroll
            for (int off = 1; off < 16; off <<= 1) mx = fmaxf(mx, __shfl_xor(mx, off, 64));
            const float mnew = fmaxf(mrow[r], mx);
            const float a = __expf(mrow[r] - mnew);
            const float e0 = __expf(s0 - mnew);
            const float e1 = __expf(s1 - mnew);
            float rs = e0 + e1;
#pragma unroll
            for (int off = 1; off < 16; off <<= 1) rs += __shfl_xor(rs, off, 64);
            lrow[r] = lrow[r] * a + rs;
            mrow[r] = mnew;
            alpha[r] = a;
            p0[r] = e0;
            p1[r] = e1;
        }
#pragma unroll
        for (int dc = 0; dc < 8; ++dc)
#pragma unroll
            for (int r = 0; r < 4; ++r) o[dc][r] *= alpha[r];

        // P: C-layout -> LDS -> A-layout (per-wave private region)
#pragma unroll
        for (int r = 0; r < 4; ++r) {
            Ps[wave * 512 + (quad * 4 + r) * 32 + l15] = (bf16)p0[r];
            Ps[wave * 512 + (quad * 4 + r) * 32 + 16 + l15] = (bf16)p1[r];
        }
        asm volatile("s_waitcnt lgkmcnt(0)" ::: "memory");
        bf16x8 pf = *(const bf16x8*)&Ps[wave * 512 + l15 * 32 + quad * 8];
#pragma unroll
        for (int dc = 0; dc < 8; ++dc) {
            bf16x8 vf = *(const bf16x8*)&Vs[(dc * 16 + l15) * 32 + quad * 8];
            o[dc] = __builtin_amdgcn_mfma_f32_16x16x32_bf16(pf, vf, o[dc], 0, 0, 0);
        }
        __syncthreads();
    }

    // normalize + write (B,S,H*D) bf16
#pragma unroll
    for (int r = 0; r < 4; ++r) {
        const int qi = qw0 + quad * 4 + r;
        const float inv = 1.0f / lrow[r];
        bf16* obase = Out + (size_t)(b * S_ + qi) * HD_ + h * 128;
#pragma unroll
        for (int dc = 0; dc < 8; ++dc) obase[dc * 16 + l15] = (bf16)(o[dc][r] * inv);
    }
}

// ---------------- launch ----------------
extern "C" void kernel_launch(void* const* d_in, const int* in_sizes, int n_in, void* d_out,
                              int out_size, void* d_ws, size_t ws_size, hipStream_t stream) {
    const float* x = (const float*)d_in[0];
    const float* cosp = (const float*)d_in[1];
    const float* sinp = (const float*)d_in[2];
    const float* Wq = (const float*)d_in[3];
    const float* Wk = (const float*)d_in[4];
    const float* Wv = (const float*)d_in[5];
    const float* Wo = (const float*)d_in[6];
    float* out = (float*)d_out;

    constexpr size_t MB = 1ull << 20;
    char* ws = (char*)d_ws;
    bf16* xb    = (bf16*)(ws + 0);         // 4096x2048        16 MB
    bf16* wqkv  = (bf16*)(ws + 16 * MB);   // 3072x2048        12 MB
    bf16* wo    = (bf16*)(ws + 28 * MB);   // 2048x2048         8 MB
    bf16* qkv   = (bf16*)(ws + 36 * MB);   // 4096x3072        24 MB
    bf16* qn    = (bf16*)(ws + 60 * MB);   // (B,H,S,D)        16 MB
    bf16* kn    = (bf16*)(ws + 76 * MB);   // (B,KV,S,D)        4 MB
    bf16* vt    = (bf16*)(ws + 80 * MB);   // (B,KV,D,S)        4 MB
    bf16* attnb = (bf16*)(ws + 84 * MB);   // (B,S,H*D)        16 MB

    // fp32 -> bf16
    cvt_f32_bf16<<<8192, 256, 0, stream>>>(x, xb, 8388608);
    cvt_f32_bf16<<<4096, 256, 0, stream>>>(Wq, wqkv, 4194304);
    cvt_f32_bf16<<<1024, 256, 0, stream>>>(Wk, wqkv + 4194304, 1048576);
    cvt_f32_bf16<<<1024, 256, 0, stream>>>(Wv, wqkv + 5242880, 1048576);
    cvt_f32_bf16<<<4096, 256, 0, stream>>>(Wo, wo, 4194304);

    // fused QKV projection: (4096,2048) x (3072,2048)^T -> (4096,3072)
    gemm_bt<bf16><<<dim3(32, 24), 256, 0, stream>>>(xb, wqkv, qkv, 2048, 3072);

    // RoPE + RMSNorm + V transpose
    rope_norm<<<24576, 256, 0, stream>>>(qkv, cosp, sinp, qn, kn, vt);

    // sliding-window flash attention
    attn_fwd<<<dim3(32, 16, 2), 256, 0, stream>>>(qn, kn, vt, attnb);

    // output projection: (4096,2048) x (2048,2048)^T -> fp32 out
    gemm_bt<float><<<dim3(32, 16), 256, 0, stream>>>(attnb, wo, out, 2048, 2048);
}

// Round 2
// 330.717 us; speedup vs baseline: 1.3114x; 1.3114x over previous
//
#include <hip/hip_runtime.h>
#include <stdint.h>

using bf16 = __bf16;
typedef __bf16 bf16x8 __attribute__((ext_vector_type(8)));
typedef __bf16 bf16x4 __attribute__((ext_vector_type(4)));
typedef float f32x4 __attribute__((ext_vector_type(4)));

#define H_ 16
#define KV_ 4
#define D_ 128
#define WIN_ 1024
#define B_ 2
#define S_ 2048
#define E_ 2048
#define HD_ 2048
#define NQKV_ 3072

// async global->LDS, 16B per lane. LDS dest must be wave-uniform base + lane*16.
__device__ __forceinline__ void gld_lds16(const void* gptr, void* lptr) {
    __builtin_amdgcn_global_load_lds(
        (__attribute__((address_space(1))) void*)(uintptr_t)gptr,
        (__attribute__((address_space(3))) void*)(uintptr_t)lptr, 16, 0, 0);
}

// ---------------- fp32 -> bf16 conversion ----------------
__global__ __launch_bounds__(256) void cvt_f32_bf16(const float* __restrict__ src,
                                                    bf16* __restrict__ dst, int n) {
    int i = (blockIdx.x * 256 + threadIdx.x) * 4;
    if (i >= n) return;
    const float4 v = *(const float4*)(src + i);
    bf16x4 o = {(bf16)v.x, (bf16)v.y, (bf16)v.z, (bf16)v.w};
    *(bf16x4*)(dst + i) = o;
}

// ---------------- GEMM: C[m,n] = sum_k A[m,k] * W[n,k]  (W row-major (N,K)) ----------------
// 128x128 tile, BK=32, 4 waves each 64x64, 16x16x32 bf16 MFMA.
template <typename OutT>
__global__ __launch_bounds__(256) void gemm_bt(const bf16* __restrict__ A,
                                               const bf16* __restrict__ W,
                                               OutT* __restrict__ C, int K, int ldc) {
    __shared__ alignas(16) bf16 As[128 * 32];
    __shared__ alignas(16) bf16 Bs[128 * 32];
    const int t = threadIdx.x;
    const int lane = t & 63;
    const int wave = t >> 6;
    const int l15 = lane & 15;
    const int quad = lane >> 4;
    const int wm = (wave & 1) * 64;
    const int wn = (wave >> 1) * 64;
    const int m0 = blockIdx.x * 128;
    const int n0 = blockIdx.y * 128;

    f32x4 acc[4][4] = {};

    const int sr = t >> 2;       // 0..63
    const int sc = (t & 3) * 8;  // 0,8,16,24
    const bf16* Ap = A + (size_t)(m0 + sr) * K + sc;
    const bf16* Wp = W + (size_t)(n0 + sr) * K + sc;
    bf16* As0 = &As[t * 8];
    bf16* As1 = &As[64 * 32 + t * 8];
    bf16* Bs0 = &Bs[t * 8];
    bf16* Bs1 = &Bs[64 * 32 + t * 8];
    const size_t rowskip = (size_t)64 * K;

    for (int k0 = 0; k0 < K; k0 += 32) {
        gld_lds16(Ap + k0, As0);
        gld_lds16(Ap + k0 + rowskip, As1);
        gld_lds16(Wp + k0, Bs0);
        gld_lds16(Wp + k0 + rowskip, Bs1);
        __syncthreads();
        bf16x8 af[4], bfr[4];
#pragma unroll
        for (int i = 0; i < 4; ++i) {
            af[i] = *(const bf16x8*)&As[(wm + i * 16 + l15) * 32 + quad * 8];
            bfr[i] = *(const bf16x8*)&Bs[(wn + i * 16 + l15) * 32 + quad * 8];
        }
#pragma unroll
        for (int i = 0; i < 4; ++i)
#pragma unroll
            for (int j = 0; j < 4; ++j)
                acc[i][j] =
                    __builtin_amdgcn_mfma_f32_16x16x32_bf16(af[i], bfr[j], acc[i][j], 0, 0, 0);
        __syncthreads();
    }
#pragma unroll
    for (int i = 0; i < 4; ++i) {
        const int row = m0 + wm + i * 16 + quad * 4;
#pragma unroll
        for (int j = 0; j < 4; ++j) {
            const int col = n0 + wn + j * 16 + l15;
#pragma unroll
            for (int r = 0; r < 4; ++r) C[(size_t)(row + r) * ldc + col] = (OutT)acc[i][j][r];
        }
    }
}

// ---------------- RoPE + RMSNorm (+transpose) ----------------
__global__ __launch_bounds__(256) void rope_norm(const bf16* __restrict__ qkv,
                                                 const float* __restrict__ cosp,
                                                 const float* __restrict__ sinp,
                                                 bf16* __restrict__ qn, bf16* __restrict__ kn,
                                                 bf16* __restrict__ vt) {
    const int unit = blockIdx.x * 4 + (threadIdx.x >> 6);
    const int lane = threadIdx.x & 63;
    const int b = unit / (S_ * 24);
    const int rem = unit - b * (S_ * 24);
    const int s = rem / 24;
    const int j = rem - s * 24;
    const size_t rowbase = (size_t)(b * S_ + s) * NQKV_;
    const float eps = 1.1920929e-7f;

    if (j < 20) {
        const bf16* src = qkv + rowbase + ((j < 16) ? (j * 128) : (2048 + (j - 16) * 128));
        float x1 = (float)src[lane];
        float x2 = (float)src[lane + 64];
        float c = cosp[s * 64 + lane];
        float sn = sinp[s * 64 + lane];
        float y1 = x1 * c + x2 * sn;
        float y2 = -x1 * sn + x2 * c;
        float ss = y1 * y1 + y2 * y2;
#pragma unroll
        for (int off = 1; off < 64; off <<= 1) ss += __shfl_xor(ss, off, 64);
        float r = rsqrtf(ss * (1.0f / 128.0f) + eps);
        if (j < 16) {
            r *= 0.12751740f;  // D^-0.5 * log2(e) folded into q (exp2-domain softmax)
            bf16* dst = qn + (size_t)((b * H_ + j) * S_ + s) * 128;
            dst[lane] = (bf16)(y1 * r);
            dst[lane + 64] = (bf16)(y2 * r);
        } else {
            bf16* dst = kn + (size_t)((b * KV_ + (j - 16)) * S_ + s) * 128;
            dst[lane] = (bf16)(y1 * r);
            dst[lane + 64] = (bf16)(y2 * r);
        }
    } else {
        const int jv = j - 20;
        const bf16* src = qkv + rowbase + 2560 + jv * 128;
        bf16* dst = vt + (size_t)(b * KV_ + jv) * 128 * S_ + s;
        dst[(size_t)lane * S_] = src[lane];
        dst[(size_t)(lane + 64) * S_] = src[lane + 64];
    }
}

// ---------------- flash attention, sliding window, S^T orientation ----------------
// Computes S^T = K*Q^T (row=key, col=q) so softmax reduces mostly in-lane, and
// O^T = V^T * P^T. All LDS tiles XOR-swizzled (16B unit ^= row&7) -> conflict-free b128.
__global__ __launch_bounds__(256, 4) void attn_fwd(const bf16* __restrict__ Qn,
                                                   const bf16* __restrict__ Kn,
                                                   const bf16* __restrict__ Vt,
                                                   bf16* __restrict__ Out) {
    __shared__ alignas(16) bf16 Ks[64 * 128];      // row=key, 16 units/row, swizzled
    __shared__ alignas(16) bf16 Vs[128 * 64];      // row=d,   8 units/row, swizzled
    __shared__ alignas(16) bf16 Ps[4 * 16 * 64];   // per-wave, row=q(l15), swizzled

    const int t = threadIdx.x;
    const int lane = t & 63;
    const int wave = t >> 6;
    const int l15 = lane & 15;
    const int quad = lane >> 4;
    const int swz = l15 & 7;
    const int qb0 = blockIdx.x * 64;
    const int h = blockIdx.y;
    const int b = blockIdx.z;
    const int hk = h >> 2;
    const int qw0 = qb0 + wave * 16;

    // Q fragment (B-operand): B[n=l15=q][k=quad*8+j]
    const bf16* qbase = Qn + ((size_t)((b * H_ + h) * S_) + qw0 + l15) * 128;
    bf16x8 qf[4];
#pragma unroll
    for (int c4 = 0; c4 < 4; ++c4) qf[c4] = *(const bf16x8*)(qbase + c4 * 32 + quad * 8);

    f32x4 o[8] = {};
    float m = -1e30f, lsum = 0.0f;

    const bf16* kroot = Kn + (size_t)((b * KV_ + hk) * S_) * 128;
    const bf16* vroot = Vt + (size_t)((b * KV_ + hk) * 128) * S_;

    // staging: swizzled source offsets (constant per thread)
    const int ku = (t & 15) ^ ((t >> 4) & 7);   // Ks: 16 units/row, 16 thr/row
    const int krow = t >> 4;                    // 0..15 (+16 per call)
    const int vu = (t & 7) ^ ((t >> 3) & 7);    // Vs: 8 units/row, 8 thr/row
    const int vrow = t >> 3;                    // 0..31 (+32 per call)
    const bf16* kst = kroot + (size_t)krow * 128 + ku * 8;
    const bf16* vst = vroot + (size_t)vrow * S_ + vu * 8;
    bf16* ksl = &Ks[t * 8];
    bf16* vsl = &Vs[t * 8];

    int lo = qb0 - (WIN_ - 1);
    if (lo < 0) lo = 0;
    const int kb_start = lo & ~63;
    const int kb_end = qb0 + 64;

    for (int kb = kb_start; kb < kb_end; kb += 64) {
#pragma unroll
        for (int c = 0; c < 4; ++c) gld_lds16(kst + (size_t)(kb + c * 16) * 128, ksl + c * 2048);
#pragma unroll
        for (int c = 0; c < 4; ++c) gld_lds16(vst + (size_t)(c * 32) * S_ + kb, vsl + c * 2048);
        __syncthreads();

        const bool wave_active = (kb + 63 >= qw0 - (WIN_ - 1));
        if (wave_active) {
            // S^T = K * Q^T : D[row=key_local][col=q]
            f32x4 sacc[4] = {};
#pragma unroll
            for (int kblk = 0; kblk < 4; ++kblk)
#pragma unroll
                for (int c4 = 0; c4 < 4; ++c4) {
                    bf16x8 kf = *(const bf16x8*)&Ks[(kblk * 16 + l15) * 128 +
                                                    (((c4 * 4 + quad) ^ swz) * 8)];
                    sacc[kblk] =
                        __builtin_amdgcn_mfma_f32_16x16x32_bf16(kf, qf[c4], sacc[kblk], 0, 0, 0);
                }

            const int q = qw0 + l15;
            float sv[16];
            const bool interior = (kb + 63 <= qw0) && (kb >= qw0 + 15 - (WIN_ - 1));
            if (interior) {
#pragma unroll
                for (int kblk = 0; kblk < 4; ++kblk)
#pragma unroll
                    for (int r = 0; r < 4; ++r) sv[kblk * 4 + r] = sacc[kblk][r];
            } else {
#pragma unroll
                for (int kblk = 0; kblk < 4; ++kblk)
#pragma unroll
                    for (int r = 0; r < 4; ++r) {
                        const int key = kb + kblk * 16 + quad * 4 + r;
                        const bool valid = (key <= q) && (q - key < WIN_);
                        sv[kblk * 4 + r] = valid ? sacc[kblk][r] : -1e30f;
                    }
            }
            // softmax (exp2 domain; scale folded into q)
            float mc = sv[0];
#pragma unroll
            for (int i = 1; i < 16; ++i) mc = fmaxf(mc, sv[i]);
            mc = fmaxf(mc, __shfl_xor(mc, 16, 64));
            mc = fmaxf(mc, __shfl_xor(mc, 32, 64));
            const float mnew = fmaxf(m, mc);
            const float al = __builtin_amdgcn_exp2f(m - mnew);
            float ls = 0.0f;
#pragma unroll
            for (int i = 0; i < 16; ++i) {
                sv[i] = __builtin_amdgcn_exp2f(sv[i] - mnew);
                ls += sv[i];
            }
            ls += __shfl_xor(ls, 16, 64);
            ls += __shfl_xor(ls, 32, 64);
            lsum = lsum * al + ls;
            m = mnew;
#pragma unroll
            for (int dblk = 0; dblk < 8; ++dblk) o[dblk] *= al;

            // P^T (C-layout) -> Ps[q=l15][key], swizzled, per-wave private
            bf16* pw = &Ps[wave * 1024 + l15 * 64];
#pragma unroll
            for (int kblk = 0; kblk < 4; ++kblk) {
                bf16x4 pb = {(bf16)sv[kblk * 4 + 0], (bf16)sv[kblk * 4 + 1],
                             (bf16)sv[kblk * 4 + 2], (bf16)sv[kblk * 4 + 3]};
                const int phys = (kblk * 2 + (quad >> 1)) ^ swz;
                *(bf16x4*)&pw[phys * 8 + (quad & 1) * 4] = pb;
            }
            // O^T += V^T * P^T
#pragma unroll
            for (int kc = 0; kc < 2; ++kc) {
                const int up = ((kc * 4 + quad) ^ swz) * 8;
                bf16x8 pfv = *(const bf16x8*)&pw[up];
#pragma unroll
                for (int dblk = 0; dblk < 8; ++dblk) {
                    bf16x8 vf = *(const bf16x8*)&Vs[(dblk * 16 + l15) * 64 + up];
                    o[dblk] = __builtin_amdgcn_mfma_f32_16x16x32_bf16(vf, pfv, o[dblk], 0, 0, 0);
                }
            }
        }
        __syncthreads();
    }

    // normalize + write: lane(quad,l15) holds O[q=qw0+l15][d=dblk*16+quad*4+r]
    const float inv = 1.0f / lsum;
    const int q = qw0 + l15;
    bf16* ob = Out + (size_t)(b * S_ + q) * HD_ + h * 128;
#pragma unroll
    for (int dblk = 0; dblk < 8; ++dblk) {
        bf16x4 ov = {(bf16)(o[dblk][0] * inv), (bf16)(o[dblk][1] * inv),
                     (bf16)(o[dblk][2] * inv), (bf16)(o[dblk][3] * inv)};
        *(bf16x4*)&ob[dblk * 16 + quad * 4] = ov;
    }
}

// ---------------- launch ----------------
extern "C" void kernel_launch(void* const* d_in, const int* in_sizes, int n_in, void* d_out,
                              int out_size, void* d_ws, size_t ws_size, hipStream_t stream) {
    const float* x = (const float*)d_in[0];
    const float* cosp = (const float*)d_in[1];
    const float* sinp = (const float*)d_in[2];
    const float* Wq = (const float*)d_in[3];
    const float* Wk = (const float*)d_in[4];
    const float* Wv = (const float*)d_in[5];
    const float* Wo = (const float*)d_in[6];
    float* out = (float*)d_out;

    constexpr size_t MB = 1ull << 20;
    char* ws = (char*)d_ws;
    bf16* xb    = (bf16*)(ws + 0);         // 4096x2048        16 MB
    bf16* wqkv  = (bf16*)(ws + 16 * MB);   // 3072x2048        12 MB
    bf16* wo    = (bf16*)(ws + 28 * MB);   // 2048x2048         8 MB
    bf16* qkv   = (bf16*)(ws + 36 * MB);   // 4096x3072        24 MB
    bf16* qn    = (bf16*)(ws + 60 * MB);   // (B,H,S,D)        16 MB
    bf16* kn    = (bf16*)(ws + 76 * MB);   // (B,KV,S,D)        4 MB
    bf16* vt    = (bf16*)(ws + 80 * MB);   // (B,KV,D,S)        4 MB
    bf16* attnb = (bf16*)(ws + 84 * MB);   // (B,S,H*D)        16 MB

    cvt_f32_bf16<<<8192, 256, 0, stream>>>(x, xb, 8388608);
    cvt_f32_bf16<<<4096, 256, 0, stream>>>(Wq, wqkv, 4194304);
    cvt_f32_bf16<<<1024, 256, 0, stream>>>(Wk, wqkv + 4194304, 1048576);
    cvt_f32_bf16<<<1024, 256, 0, stream>>>(Wv, wqkv + 5242880, 1048576);
    cvt_f32_bf16<<<4096, 256, 0, stream>>>(Wo, wo, 4194304);

    gemm_bt<bf16><<<dim3(32, 24), 256, 0, stream>>>(xb, wqkv, qkv, 2048, 3072);
    rope_norm<<<24576, 256, 0, stream>>>(qkv, cosp, sinp, qn, kn, vt);
    attn_fwd<<<dim3(32, 16, 2), 256, 0, stream>>>(qn, kn, vt, attnb);
    gemm_bt<float><<<dim3(32, 16), 256, 0, stream>>>(attnb, wo, out, 2048, 2048);
}

// Round 4
// 311.783 us; speedup vs baseline: 1.3911x; 1.0607x over previous
//
#include <hip/hip_runtime.h>
#include <stdint.h>

using bf16 = __bf16;
typedef __bf16 bf16x8 __attribute__((ext_vector_type(8)));
typedef __bf16 bf16x4 __attribute__((ext_vector_type(4)));
typedef float f32x4 __attribute__((ext_vector_type(4)));

#define H_ 16
#define KV_ 4
#define D_ 128
#define WIN_ 1024
#define B_ 2
#define S_ 2048
#define E_ 2048
#define HD_ 2048

// async global->LDS, 16B per lane. LDS dest must be wave-uniform base + lane*16.
__device__ __forceinline__ void gld_lds16(const void* gptr, void* lptr) {
    __builtin_amdgcn_global_load_lds(
        (__attribute__((address_space(1))) void*)(uintptr_t)gptr,
        (__attribute__((address_space(3))) void*)(uintptr_t)lptr, 16, 0, 0);
}

// ---------------- fused fp32 -> bf16 conversion (x, Wq, Wk, Wv, Wo -> one contiguous dst) ----
__global__ __launch_bounds__(256) void cvt_all(const float* __restrict__ x,
                                               const float* __restrict__ wq,
                                               const float* __restrict__ wk,
                                               const float* __restrict__ wv,
                                               const float* __restrict__ wo,
                                               bf16* __restrict__ dst) {
    int i = (blockIdx.x * 256 + threadIdx.x) * 4;  // into 18,874,368-elem concatenation
    const float* src;
    int off;
    if (i < 8388608)       { src = x;  off = 0; }
    else if (i < 12582912) { src = wq; off = 8388608; }
    else if (i < 13631488) { src = wk; off = 12582912; }
    else if (i < 14680064) { src = wv; off = 13631488; }
    else                   { src = wo; off = 14680064; }
    const float4 v = *(const float4*)(src + (i - off));
    bf16x4 o = {(bf16)v.x, (bf16)v.y, (bf16)v.z, (bf16)v.w};
    *(bf16x4*)(dst + i) = o;
}

// swizzled staging/fragment scheme:
//  physical 16B unit p of LDS row r holds global unit p ^ ((r>>1)&3)
//  -> half-wave b128 fragment reads hit all 32 banks (conflict-free)

// ---------------- GEMM: C[m,n] = sum_k A[m,k] * W[n,k] (plain epilogue; out-proj) ----------
template <typename OutT>
__global__ __launch_bounds__(256) void gemm_bt(const bf16* __restrict__ A,
                                               const bf16* __restrict__ W,
                                               OutT* __restrict__ C, int K, int ldc) {
    __shared__ alignas(16) bf16 As[128 * 32];
    __shared__ alignas(16) bf16 Bs[128 * 32];
    const int t = threadIdx.x;
    const int lane = t & 63;
    const int wave = t >> 6;
    const int l15 = lane & 15;
    const int quad = lane >> 4;
    const int fsw = (l15 >> 1) & 3;  // fragment-read swizzle
    const int wm = (wave & 1) * 64;
    const int wn = (wave >> 1) * 64;
    const int m0 = blockIdx.x * 128;
    const int n0 = blockIdx.y * 128;

    f32x4 acc[4][4] = {};

    const int sr = t >> 2;
    const int sc = ((t & 3) ^ ((t >> 3) & 3)) * 8;  // swizzled source unit
    const bf16* Ap = A + (size_t)(m0 + sr) * K + sc;
    const bf16* Wp = W + (size_t)(n0 + sr) * K + sc;
    bf16* As0 = &As[t * 8];
    bf16* As1 = &As[64 * 32 + t * 8];
    bf16* Bs0 = &Bs[t * 8];
    bf16* Bs1 = &Bs[64 * 32 + t * 8];
    const size_t rowskip = (size_t)64 * K;

    for (int k0 = 0; k0 < K; k0 += 32) {
        gld_lds16(Ap + k0, As0);
        gld_lds16(Ap + k0 + rowskip, As1);
        gld_lds16(Wp + k0, Bs0);
        gld_lds16(Wp + k0 + rowskip, Bs1);
        __syncthreads();
        bf16x8 af[4], bfr[4];
#pragma unroll
        for (int i = 0; i < 4; ++i) {
            af[i] = *(const bf16x8*)&As[(wm + i * 16 + l15) * 32 + ((quad ^ fsw) * 8)];
            bfr[i] = *(const bf16x8*)&Bs[(wn + i * 16 + l15) * 32 + ((quad ^ fsw) * 8)];
        }
#pragma unroll
        for (int i = 0; i < 4; ++i)
#pragma unroll
            for (int j = 0; j < 4; ++j)
                acc[i][j] =
                    __builtin_amdgcn_mfma_f32_16x16x32_bf16(af[i], bfr[j], acc[i][j], 0, 0, 0);
        __syncthreads();
    }
#pragma unroll
    for (int i = 0; i < 4; ++i) {
        const int row = m0 + wm + i * 16 + quad * 4;
#pragma unroll
        for (int j = 0; j < 4; ++j) {
            const int col = n0 + wn + j * 16 + l15;
#pragma unroll
            for (int r = 0; r < 4; ++r) C[(size_t)(row + r) * ldc + col] = (OutT)acc[i][j][r];
        }
    }
}

// ---------------- QKV GEMM with fused RoPE + RMSNorm + V-transpose epilogue ----------------
// grid.y = 24 units: 0..15 q heads, 16..19 k heads, 20..23 v heads. Each N-tile of 128
// is exactly one head, so the block owns the full normalization group.
__global__ __launch_bounds__(256) void gemm_qkv_rope(const bf16* __restrict__ A,
                                                     const bf16* __restrict__ W,
                                                     const float* __restrict__ cosp,
                                                     const float* __restrict__ sinp,
                                                     bf16* __restrict__ qn,
                                                     bf16* __restrict__ kn,
                                                     bf16* __restrict__ vt) {
    __shared__ alignas(16) bf16 As[128 * 32];
    __shared__ alignas(16) bf16 Bs[128 * 32];
    __shared__ alignas(16) bf16 Cs[128 * 136];  // +8 pad: conflict-free epilogue reads
    const int t = threadIdx.x;
    const int lane = t & 63;
    const int wave = t >> 6;
    const int l15 = lane & 15;
    const int quad = lane >> 4;
    const int fsw = (l15 >> 1) & 3;
    const int wm = (wave & 1) * 64;
    const int wn = (wave >> 1) * 64;
    const int m0 = blockIdx.x * 128;
    const int n0 = blockIdx.y * 128;
    const int K = E_;

    f32x4 acc[4][4] = {};

    const int sr = t >> 2;
    const int sc = ((t & 3) ^ ((t >> 3) & 3)) * 8;
    const bf16* Ap = A + (size_t)(m0 + sr) * K + sc;
    const bf16* Wp = W + (size_t)(n0 + sr) * K + sc;
    bf16* As0 = &As[t * 8];
    bf16* As1 = &As[64 * 32 + t * 8];
    bf16* Bs0 = &Bs[t * 8];
    bf16* Bs1 = &Bs[64 * 32 + t * 8];
    const size_t rowskip = (size_t)64 * K;

    for (int k0 = 0; k0 < K; k0 += 32) {
        gld_lds16(Ap + k0, As0);
        gld_lds16(Ap + k0 + rowskip, As1);
        gld_lds16(Wp + k0, Bs0);
        gld_lds16(Wp + k0 + rowskip, Bs1);
        __syncthreads();
        bf16x8 af[4], bfr[4];
#pragma unroll
        for (int i = 0; i < 4; ++i) {
            af[i] = *(const bf16x8*)&As[(wm + i * 16 + l15) * 32 + ((quad ^ fsw) * 8)];
            bfr[i] = *(const bf16x8*)&Bs[(wn + i * 16 + l15) * 32 + ((quad ^ fsw) * 8)];
        }
#pragma unroll
        for (int i = 0; i < 4; ++i)
#pragma unroll
            for (int j = 0; j < 4; ++j)
                acc[i][j] =
                    __builtin_amdgcn_mfma_f32_16x16x32_bf16(af[i], bfr[j], acc[i][j], 0, 0, 0);
        __syncthreads();
    }

    // stash tile to LDS (bf16, same rounding the old qkv global buffer had)
#pragma unroll
    for (int i = 0; i < 4; ++i) {
        const int row = wm + i * 16 + quad * 4;
#pragma unroll
        for (int j = 0; j < 4; ++j) {
            const int col = wn + j * 16 + l15;
#pragma unroll
            for (int r = 0; r < 4; ++r) Cs[(row + r) * 136 + col] = (bf16)acc[i][j][r];
        }
    }
    __syncthreads();

    const int unit = n0 >> 7;  // == blockIdx.y
    if (unit < 20) {
        // 2 threads per token row; each handles d = half*32 .. half*32+31
        const int row = t >> 1;
        const int half = t & 1;
        const int gr = m0 + row;
        const int bb = gr >> 11;
        const int s = gr & 2047;
        const bf16* crow = &Cs[row * 136 + half * 32];
        const float* cp = cosp + s * 64 + half * 32;
        const float* sp = sinp + s * 64 + half * 32;
        bf16x8 xa[4], xb2[4];
#pragma unroll
        for (int u = 0; u < 4; ++u) {
            xa[u] = *(const bf16x8*)(crow + u * 8);
            xb2[u] = *(const bf16x8*)(crow + 64 + u * 8);
        }
        float y1[32], y2[32], ss = 0.0f;
#pragma unroll
        for (int u = 0; u < 4; ++u)
#pragma unroll
            for (int e = 0; e < 8; ++e) {
                const int jj = u * 8 + e;
                const float x1 = (float)xa[u][e];
                const float x2 = (float)xb2[u][e];
                const float c = cp[jj];
                const float sn = sp[jj];
                y1[jj] = x1 * c + x2 * sn;
                y2[jj] = x2 * c - x1 * sn;
                ss += y1[jj] * y1[jj] + y2[jj] * y2[jj];
            }
        ss += __shfl_xor(ss, 1, 64);
        float rr = rsqrtf(ss * (1.0f / 128.0f) + 1.1920929e-7f);
        bf16* dst;
        if (unit < 16) {
            rr *= 0.12751740f;  // D^-0.5 * log2(e): exp2-domain softmax in attn
            dst = qn + ((size_t)(bb * H_ + unit) * S_ + s) * 128 + half * 32;
        } else {
            dst = kn + ((size_t)(bb * KV_ + (unit - 16)) * S_ + s) * 128 + half * 32;
        }
#pragma unroll
        for (int u = 0; u < 4; ++u) {
            bf16x8 p1, p2;
#pragma unroll
            for (int e = 0; e < 8; ++e) {
                p1[e] = (bf16)(y1[u * 8 + e] * rr);
                p2[e] = (bf16)(y2[u * 8 + e] * rr);
            }
            *(bf16x8*)(dst + u * 8) = p1;
            *(bf16x8*)(dst + 64 + u * 8) = p2;
        }
    } else {
        // V: transpose tile -> vt[(b,jv,d,s)], thread owns one d, 64 s-positions
        const int jv = unit - 20;
        const int d = t >> 1;
        const int sl0 = (t & 1) * 64;
        const int s0 = (m0 & 2047) + sl0;
        const int bb = m0 >> 11;
        bf16* vdst = vt + ((size_t)(bb * KV_ + jv) * 128 + d) * S_ + s0;
#pragma unroll
        for (int u = 0; u < 8; ++u) {
            bf16x8 pk;
#pragma unroll
            for (int e = 0; e < 8; ++e) pk[e] = Cs[(sl0 + u * 8 + e) * 136 + d];
            *(bf16x8*)(vdst + u * 8) = pk;
        }
    }
}

// ---------------- flash attention, sliding window, S^T orientation ----------------
__global__ __launch_bounds__(256, 4) void attn_fwd(const bf16* __restrict__ Qn,
                                                   const bf16* __restrict__ Kn,
                                                   const bf16* __restrict__ Vt,
                                                   bf16* __restrict__ Out) {
    __shared__ alignas(16) bf16 Ks[64 * 128];
    __shared__ alignas(16) bf16 Vs[128 * 64];
    __shared__ alignas(16) bf16 Ps[4 * 16 * 64];

    const int t = threadIdx.x;
    const int lane = t & 63;
    const int wave = t >> 6;
    const int l15 = lane & 15;
    const int quad = lane >> 4;
    const int swz = l15 & 7;
    const int qb0 = blockIdx.x * 64;
    const int h = blockIdx.y;
    const int b = blockIdx.z;
    const int hk = h >> 2;
    const int qw0 = qb0 + wave * 16;

    const bf16* qbase = Qn + ((size_t)((b * H_ + h) * S_) + qw0 + l15) * 128;
    bf16x8 qf[4];
#pragma unroll
    for (int c4 = 0; c4 < 4; ++c4) qf[c4] = *(const bf16x8*)(qbase + c4 * 32 + quad * 8);

    f32x4 o[8] = {};
    float m = -1e30f, lsum = 0.0f;

    const bf16* kroot = Kn + (size_t)((b * KV_ + hk) * S_) * 128;
    const bf16* vroot = Vt + (size_t)((b * KV_ + hk) * 128) * S_;

    const int ku = (t & 15) ^ ((t >> 4) & 7);
    const int krow = t >> 4;
    const int vu = (t & 7) ^ ((t >> 3) & 7);
    const int vrow = t >> 3;
    const bf16* kst = kroot + (size_t)krow * 128 + ku * 8;
    const bf16* vst = vroot + (size_t)vrow * S_ + vu * 8;
    bf16* ksl = &Ks[t * 8];
    bf16* vsl = &Vs[t * 8];

    int lo = qb0 - (WIN_ - 1);
    if (lo < 0) lo = 0;
    const int kb_start = lo & ~63;
    const int kb_end = qb0 + 64;

    for (int kb = kb_start; kb < kb_end; kb += 64) {
#pragma unroll
        for (int c = 0; c < 4; ++c) gld_lds16(kst + (size_t)(kb + c * 16) * 128, ksl + c * 2048);
#pragma unroll
        for (int c = 0; c < 4; ++c) gld_lds16(vst + (size_t)(c * 32) * S_ + kb, vsl + c * 2048);
        __syncthreads();

        const bool wave_active = (kb + 63 >= qw0 - (WIN_ - 1));
        if (wave_active) {
            f32x4 sacc[4] = {};
#pragma unroll
            for (int kblk = 0; kblk < 4; ++kblk)
#pragma unroll
                for (int c4 = 0; c4 < 4; ++c4) {
                    bf16x8 kf = *(const bf16x8*)&Ks[(kblk * 16 + l15) * 128 +
                                                    (((c4 * 4 + quad) ^ swz) * 8)];
                    sacc[kblk] =
                        __builtin_amdgcn_mfma_f32_16x16x32_bf16(kf, qf[c4], sacc[kblk], 0, 0, 0);
                }

            const int q = qw0 + l15;
            float sv[16];
            const bool interior = (kb + 63 <= qw0) && (kb >= qw0 + 15 - (WIN_ - 1));
            if (interior) {
#pragma unroll
                for (int kblk = 0; kblk < 4; ++kblk)
#pragma unroll
                    for (int r = 0; r < 4; ++r) sv[kblk * 4 + r] = sacc[kblk][r];
            } else {
#pragma unroll
                for (int kblk = 0; kblk < 4; ++kblk)
#pragma unroll
                    for (int r = 0; r < 4; ++r) {
                        const int key = kb + kblk * 16 + quad * 4 + r;
                        const bool valid = (key <= q) && (q - key < WIN_);
                        sv[kblk * 4 + r] = valid ? sacc[kblk][r] : -1e30f;
                    }
            }
            float mc = sv[0];
#pragma unroll
            for (int i = 1; i < 16; ++i) mc = fmaxf(mc, sv[i]);
            mc = fmaxf(mc, __shfl_xor(mc, 16, 64));
            mc = fmaxf(mc, __shfl_xor(mc, 32, 64));
            const float mnew = fmaxf(m, mc);
            const float al = __builtin_amdgcn_exp2f(m - mnew);
            float ls = 0.0f;
#pragma unroll
            for (int i = 0; i < 16; ++i) {
                sv[i] = __builtin_amdgcn_exp2f(sv[i] - mnew);
                ls += sv[i];
            }
            ls += __shfl_xor(ls, 16, 64);
            ls += __shfl_xor(ls, 32, 64);
            lsum = lsum * al + ls;
            m = mnew;
#pragma unroll
            for (int dblk = 0; dblk < 8; ++dblk) o[dblk] *= al;

            bf16* pw = &Ps[wave * 1024 + l15 * 64];
#pragma unroll
            for (int kblk = 0; kblk < 4; ++kblk) {
                bf16x4 pb = {(bf16)sv[kblk * 4 + 0], (bf16)sv[kblk * 4 + 1],
                             (bf16)sv[kblk * 4 + 2], (bf16)sv[kblk * 4 + 3]};
                const int phys = (kblk * 2 + (quad >> 1)) ^ swz;
                *(bf16x4*)&pw[phys * 8 + (quad & 1) * 4] = pb;
            }
#pragma unroll
            for (int kc = 0; kc < 2; ++kc) {
                const int up = ((kc * 4 + quad) ^ swz) * 8;
                bf16x8 pfv = *(const bf16x8*)&pw[up];
#pragma unroll
                for (int dblk = 0; dblk < 8; ++dblk) {
                    bf16x8 vf = *(const bf16x8*)&Vs[(dblk * 16 + l15) * 64 + up];
                    o[dblk] = __builtin_amdgcn_mfma_f32_16x16x32_bf16(vf, pfv, o[dblk], 0, 0, 0);
                }
            }
        }
        __syncthreads();
    }

    const float inv = 1.0f / lsum;
    const int q = qw0 + l15;
    bf16* ob = Out + (size_t)(b * S_ + q) * HD_ + h * 128;
#pragma unroll
    for (int dblk = 0; dblk < 8; ++dblk) {
        bf16x4 ov = {(bf16)(o[dblk][0] * inv), (bf16)(o[dblk][1] * inv),
                     (bf16)(o[dblk][2] * inv), (bf16)(o[dblk][3] * inv)};
        *(bf16x4*)&ob[dblk * 16 + quad * 4] = ov;
    }
}

// ---------------- launch ----------------
extern "C" void kernel_launch(void* const* d_in, const int* in_sizes, int n_in, void* d_out,
                              int out_size, void* d_ws, size_t ws_size, hipStream_t stream) {
    const float* x = (const float*)d_in[0];
    const float* cosp = (const float*)d_in[1];
    const float* sinp = (const float*)d_in[2];
    const float* Wq = (const float*)d_in[3];
    const float* Wk = (const float*)d_in[4];
    const float* Wv = (const float*)d_in[5];
    const float* Wo = (const float*)d_in[6];
    float* out = (float*)d_out;

    constexpr size_t MB = 1ull << 20;
    char* ws = (char*)d_ws;
    bf16* xb    = (bf16*)(ws + 0);          // x bf16 (4096x2048)       16 MB
    bf16* wqkv  = (bf16*)(ws + 16 * MB);    // Wq|Wk|Wv bf16 (3072x2048) 12 MB
    bf16* wo    = (bf16*)(ws + 28 * MB);    // Wo bf16 (2048x2048)        8 MB
    bf16* qn    = (bf16*)(ws + 40 * MB);    // (B,H,S,D)                 16 MB
    bf16* kn    = (bf16*)(ws + 56 * MB);    // (B,KV,S,D)                 4 MB
    bf16* vt    = (bf16*)(ws + 60 * MB);    // (B,KV,D,S)                 4 MB
    bf16* attnb = (bf16*)(ws + 64 * MB);    // (B,S,H*D)                 16 MB

    // one fused cvt writes xb, wqkv, wo back-to-back (contiguous dst)
    cvt_all<<<18432, 256, 0, stream>>>(x, Wq, Wk, Wv, Wo, xb);
    gemm_qkv_rope<<<dim3(32, 24), 256, 0, stream>>>(xb, wqkv, cosp, sinp, qn, kn, vt);
    attn_fwd<<<dim3(32, 16, 2), 256, 0, stream>>>(qn, kn, vt, attnb);
    gemm_bt<float><<<dim3(32, 16), 256, 0, stream>>>(attnb, wo, out, 2048, 2048);
}

// Round 5
// 310.457 us; speedup vs baseline: 1.3970x; 1.0043x over previous
//
#include <hip/hip_runtime.h>
#include <stdint.h>

using bf16 = __bf16;
typedef __bf16 bf16x8 __attribute__((ext_vector_type(8)));
typedef __bf16 bf16x4 __attribute__((ext_vector_type(4)));
typedef float f32x4 __attribute__((ext_vector_type(4)));

#define H_ 16
#define KV_ 4
#define D_ 128
#define WIN_ 1024
#define B_ 2
#define S_ 2048
#define E_ 2048
#define HD_ 2048

// async global->LDS, 16B per lane. LDS dest must be wave-uniform base + lane*16.
__device__ __forceinline__ void gld_lds16(const void* gptr, void* lptr) {
    __builtin_amdgcn_global_load_lds(
        (__attribute__((address_space(1))) void*)(uintptr_t)gptr,
        (__attribute__((address_space(3))) void*)(uintptr_t)lptr, 16, 0, 0);
}

// ---------------- fused fp32 -> bf16 conversion (x, Wq, Wk, Wv, Wo -> one contiguous dst) ----
__global__ __launch_bounds__(256) void cvt_all(const float* __restrict__ x,
                                               const float* __restrict__ wq,
                                               const float* __restrict__ wk,
                                               const float* __restrict__ wv,
                                               const float* __restrict__ wo,
                                               bf16* __restrict__ dst) {
    int i = (blockIdx.x * 256 + threadIdx.x) * 4;  // into 18,874,368-elem concatenation
    const float* src;
    int off;
    if (i < 8388608)       { src = x;  off = 0; }
    else if (i < 12582912) { src = wq; off = 8388608; }
    else if (i < 13631488) { src = wk; off = 12582912; }
    else if (i < 14680064) { src = wv; off = 13631488; }
    else                   { src = wo; off = 14680064; }
    const float4 v = *(const float4*)(src + (i - off));
    bf16x4 o = {(bf16)v.x, (bf16)v.y, (bf16)v.z, (bf16)v.w};
    *(bf16x4*)(dst + i) = o;
}

// swizzled staging/fragment scheme:
//  physical 16B unit p of LDS row r holds global unit p ^ ((r>>1)&3)
//  -> half-wave b128 fragment reads hit all 32 banks (conflict-free)

// ---------------- GEMM: C[m,n] = sum_k A[m,k] * W[n,k] (plain epilogue; out-proj) ----------
template <typename OutT>
__global__ __launch_bounds__(256) void gemm_bt(const bf16* __restrict__ A,
                                               const bf16* __restrict__ W,
                                               OutT* __restrict__ C, int K, int ldc) {
    __shared__ alignas(16) bf16 As[128 * 32];
    __shared__ alignas(16) bf16 Bs[128 * 32];
    const int t = threadIdx.x;
    const int lane = t & 63;
    const int wave = t >> 6;
    const int l15 = lane & 15;
    const int quad = lane >> 4;
    const int fsw = (l15 >> 1) & 3;  // fragment-read swizzle
    const int wm = (wave & 1) * 64;
    const int wn = (wave >> 1) * 64;
    const int m0 = blockIdx.x * 128;
    const int n0 = blockIdx.y * 128;

    f32x4 acc[4][4] = {};

    const int sr = t >> 2;
    const int sc = ((t & 3) ^ ((t >> 3) & 3)) * 8;  // swizzled source unit
    const bf16* Ap = A + (size_t)(m0 + sr) * K + sc;
    const bf16* Wp = W + (size_t)(n0 + sr) * K + sc;
    bf16* As0 = &As[t * 8];
    bf16* As1 = &As[64 * 32 + t * 8];
    bf16* Bs0 = &Bs[t * 8];
    bf16* Bs1 = &Bs[64 * 32 + t * 8];
    const size_t rowskip = (size_t)64 * K;

    for (int k0 = 0; k0 < K; k0 += 32) {
        gld_lds16(Ap + k0, As0);
        gld_lds16(Ap + k0 + rowskip, As1);
        gld_lds16(Wp + k0, Bs0);
        gld_lds16(Wp + k0 + rowskip, Bs1);
        __syncthreads();
        bf16x8 af[4], bfr[4];
#pragma unroll
        for (int i = 0; i < 4; ++i) {
            af[i] = *(const bf16x8*)&As[(wm + i * 16 + l15) * 32 + ((quad ^ fsw) * 8)];
            bfr[i] = *(const bf16x8*)&Bs[(wn + i * 16 + l15) * 32 + ((quad ^ fsw) * 8)];
        }
#pragma unroll
        for (int i = 0; i < 4; ++i)
#pragma unroll
            for (int j = 0; j < 4; ++j)
                acc[i][j] =
                    __builtin_amdgcn_mfma_f32_16x16x32_bf16(af[i], bfr[j], acc[i][j], 0, 0, 0);
        __syncthreads();
    }
#pragma unroll
    for (int i = 0; i < 4; ++i) {
        const int row = m0 + wm + i * 16 + quad * 4;
#pragma unroll
        for (int j = 0; j < 4; ++j) {
            const int col = n0 + wn + j * 16 + l15;
#pragma unroll
            for (int r = 0; r < 4; ++r) C[(size_t)(row + r) * ldc + col] = (OutT)acc[i][j][r];
        }
    }
}

// ---------------- QKV GEMM with fused RoPE + RMSNorm + V-transpose epilogue ----------------
// grid.y = 24 units: 0..15 q heads, 16..19 k heads, 20..23 v heads. Each N-tile of 128
// is exactly one head, so the block owns the full normalization group.
// LDS: Cs (post-loop) ALIASES As/Bs (K-loop) -> 34,816 B total, 3-4 blocks/CU.
__global__ __launch_bounds__(256) void gemm_qkv_rope(const bf16* __restrict__ A,
                                                     const bf16* __restrict__ W,
                                                     const float* __restrict__ cosp,
                                                     const float* __restrict__ sinp,
                                                     bf16* __restrict__ qn,
                                                     bf16* __restrict__ kn,
                                                     bf16* __restrict__ vt) {
    __shared__ alignas(16) unsigned char smem[128 * 136 * 2];  // 34,816 B union
    bf16* As = (bf16*)smem;                 // 128*32 = 8 KB   (K-loop)
    bf16* Bs = (bf16*)(smem + 8192);        // 128*32 = 8 KB   (K-loop)
    bf16* Cs = (bf16*)smem;                 // 128*136 = 34 KB (epilogue, aliases As/Bs)
    const int t = threadIdx.x;
    const int lane = t & 63;
    const int wave = t >> 6;
    const int l15 = lane & 15;
    const int quad = lane >> 4;
    const int fsw = (l15 >> 1) & 3;
    const int wm = (wave & 1) * 64;
    const int wn = (wave >> 1) * 64;
    const int m0 = blockIdx.x * 128;
    const int n0 = blockIdx.y * 128;
    const int K = E_;

    f32x4 acc[4][4] = {};

    const int sr = t >> 2;
    const int sc = ((t & 3) ^ ((t >> 3) & 3)) * 8;
    const bf16* Ap = A + (size_t)(m0 + sr) * K + sc;
    const bf16* Wp = W + (size_t)(n0 + sr) * K + sc;
    bf16* As0 = &As[t * 8];
    bf16* As1 = &As[64 * 32 + t * 8];
    bf16* Bs0 = &Bs[t * 8];
    bf16* Bs1 = &Bs[64 * 32 + t * 8];
    const size_t rowskip = (size_t)64 * K;

    for (int k0 = 0; k0 < K; k0 += 32) {
        gld_lds16(Ap + k0, As0);
        gld_lds16(Ap + k0 + rowskip, As1);
        gld_lds16(Wp + k0, Bs0);
        gld_lds16(Wp + k0 + rowskip, Bs1);
        __syncthreads();
        bf16x8 af[4], bfr[4];
#pragma unroll
        for (int i = 0; i < 4; ++i) {
            af[i] = *(const bf16x8*)&As[(wm + i * 16 + l15) * 32 + ((quad ^ fsw) * 8)];
            bfr[i] = *(const bf16x8*)&Bs[(wn + i * 16 + l15) * 32 + ((quad ^ fsw) * 8)];
        }
#pragma unroll
        for (int i = 0; i < 4; ++i)
#pragma unroll
            for (int j = 0; j < 4; ++j)
                acc[i][j] =
                    __builtin_amdgcn_mfma_f32_16x16x32_bf16(af[i], bfr[j], acc[i][j], 0, 0, 0);
        __syncthreads();
    }
    // after the loop-end barrier all ds_reads are drained -> safe to reuse As/Bs as Cs

    // stash tile to LDS (bf16, same rounding the old qkv global buffer had)
#pragma unroll
    for (int i = 0; i < 4; ++i) {
        const int row = wm + i * 16 + quad * 4;
#pragma unroll
        for (int j = 0; j < 4; ++j) {
            const int col = wn + j * 16 + l15;
#pragma unroll
            for (int r = 0; r < 4; ++r) Cs[(row + r) * 136 + col] = (bf16)acc[i][j][r];
        }
    }
    __syncthreads();

    const int unit = n0 >> 7;  // == blockIdx.y
    if (unit < 20) {
        // 2 threads per token row; each handles d = half*32 .. half*32+31
        const int row = t >> 1;
        const int half = t & 1;
        const int gr = m0 + row;
        const int bb = gr >> 11;
        const int s = gr & 2047;
        const bf16* crow = &Cs[row * 136 + half * 32];
        const float* cp = cosp + s * 64 + half * 32;
        const float* sp = sinp + s * 64 + half * 32;
        bf16x8 xa[4], xb2[4];
#pragma unroll
        for (int u = 0; u < 4; ++u) {
            xa[u] = *(const bf16x8*)(crow + u * 8);
            xb2[u] = *(const bf16x8*)(crow + 64 + u * 8);
        }
        float y1[32], y2[32], ss = 0.0f;
#pragma unroll
        for (int u = 0; u < 4; ++u)
#pragma unroll
            for (int e = 0; e < 8; ++e) {
                const int jj = u * 8 + e;
                const float x1 = (float)xa[u][e];
                const float x2 = (float)xb2[u][e];
                const float c = cp[jj];
                const float sn = sp[jj];
                y1[jj] = x1 * c + x2 * sn;
                y2[jj] = x2 * c - x1 * sn;
                ss += y1[jj] * y1[jj] + y2[jj] * y2[jj];
            }
        ss += __shfl_xor(ss, 1, 64);
        float rr = rsqrtf(ss * (1.0f / 128.0f) + 1.1920929e-7f);
        bf16* dst;
        if (unit < 16) {
            rr *= 0.12751740f;  // D^-0.5 * log2(e): exp2-domain softmax in attn
            dst = qn + ((size_t)(bb * H_ + unit) * S_ + s) * 128 + half * 32;
        } else {
            dst = kn + ((size_t)(bb * KV_ + (unit - 16)) * S_ + s) * 128 + half * 32;
        }
#pragma unroll
        for (int u = 0; u < 4; ++u) {
            bf16x8 p1, p2;
#pragma unroll
            for (int e = 0; e < 8; ++e) {
                p1[e] = (bf16)(y1[u * 8 + e] * rr);
                p2[e] = (bf16)(y2[u * 8 + e] * rr);
            }
            *(bf16x8*)(dst + u * 8) = p1;
            *(bf16x8*)(dst + 64 + u * 8) = p2;
        }
    } else {
        // V: transpose tile -> vt[(b,jv,d,s)], thread owns one d, 64 s-positions
        const int jv = unit - 20;
        const int d = t >> 1;
        const int sl0 = (t & 1) * 64;
        const int s0 = (m0 & 2047) + sl0;
        const int bb = m0 >> 11;
        bf16* vdst = vt + ((size_t)(bb * KV_ + jv) * 128 + d) * S_ + s0;
#pragma unroll
        for (int u = 0; u < 8; ++u) {
            bf16x8 pk;
#pragma unroll
            for (int e = 0; e < 8; ++e) pk[e] = Cs[(sl0 + u * 8 + e) * 136 + d];
            *(bf16x8*)(vdst + u * 8) = pk;
        }
    }
}

// ---------------- flash attention, sliding window, S^T orientation ----------------
__global__ __launch_bounds__(256, 4) void attn_fwd(const bf16* __restrict__ Qn,
                                                   const bf16* __restrict__ Kn,
                                                   const bf16* __restrict__ Vt,
                                                   bf16* __restrict__ Out) {
    __shared__ alignas(16) bf16 Ks[64 * 128];
    __shared__ alignas(16) bf16 Vs[128 * 64];
    __shared__ alignas(16) bf16 Ps[4 * 16 * 64];

    const int t = threadIdx.x;
    const int lane = t & 63;
    const int wave = t >> 6;
    const int l15 = lane & 15;
    const int quad = lane >> 4;
    const int swz = l15 & 7;
    const int qb0 = blockIdx.x * 64;
    const int h = blockIdx.y;
    const int b = blockIdx.z;
    const int hk = h >> 2;
    const int qw0 = qb0 + wave * 16;

    const bf16* qbase = Qn + ((size_t)((b * H_ + h) * S_) + qw0 + l15) * 128;
    bf16x8 qf[4];
#pragma unroll
    for (int c4 = 0; c4 < 4; ++c4) qf[c4] = *(const bf16x8*)(qbase + c4 * 32 + quad * 8);

    f32x4 o[8] = {};
    float m = -1e30f, lsum = 0.0f;

    const bf16* kroot = Kn + (size_t)((b * KV_ + hk) * S_) * 128;
    const bf16* vroot = Vt + (size_t)((b * KV_ + hk) * 128) * S_;

    const int ku = (t & 15) ^ ((t >> 4) & 7);
    const int krow = t >> 4;
    const int vu = (t & 7) ^ ((t >> 3) & 7);
    const int vrow = t >> 3;
    const bf16* kst = kroot + (size_t)krow * 128 + ku * 8;
    const bf16* vst = vroot + (size_t)vrow * S_ + vu * 8;
    bf16* ksl = &Ks[t * 8];
    bf16* vsl = &Vs[t * 8];

    int lo = qb0 - (WIN_ - 1);
    if (lo < 0) lo = 0;
    const int kb_start = lo & ~63;
    const int kb_end = qb0 + 64;

    for (int kb = kb_start; kb < kb_end; kb += 64) {
#pragma unroll
        for (int c = 0; c < 4; ++c) gld_lds16(kst + (size_t)(kb + c * 16) * 128, ksl + c * 2048);
#pragma unroll
        for (int c = 0; c < 4; ++c) gld_lds16(vst + (size_t)(c * 32) * S_ + kb, vsl + c * 2048);
        __syncthreads();

        const bool wave_active = (kb + 63 >= qw0 - (WIN_ - 1));
        if (wave_active) {
            f32x4 sacc[4] = {};
#pragma unroll
            for (int kblk = 0; kblk < 4; ++kblk)
#pragma unroll
                for (int c4 = 0; c4 < 4; ++c4) {
                    bf16x8 kf = *(const bf16x8*)&Ks[(kblk * 16 + l15) * 128 +
                                                    (((c4 * 4 + quad) ^ swz) * 8)];
                    sacc[kblk] =
                        __builtin_amdgcn_mfma_f32_16x16x32_bf16(kf, qf[c4], sacc[kblk], 0, 0, 0);
                }

            const int q = qw0 + l15;
            float sv[16];
            const bool interior = (kb + 63 <= qw0) && (kb >= qw0 + 15 - (WIN_ - 1));
            if (interior) {
#pragma unroll
                for (int kblk = 0; kblk < 4; ++kblk)
#pragma unroll
                    for (int r = 0; r < 4; ++r) sv[kblk * 4 + r] = sacc[kblk][r];
            } else {
#pragma unroll
                for (int kblk = 0; kblk < 4; ++kblk)
#pragma unroll
                    for (int r = 0; r < 4; ++r) {
                        const int key = kb + kblk * 16 + quad * 4 + r;
                        const bool valid = (key <= q) && (q - key < WIN_);
                        sv[kblk * 4 + r] = valid ? sacc[kblk][r] : -1e30f;
                    }
            }
            float mc = sv[0];
#pragma unroll
            for (int i = 1; i < 16; ++i) mc = fmaxf(mc, sv[i]);
            mc = fmaxf(mc, __shfl_xor(mc, 16, 64));
            mc = fmaxf(mc, __shfl_xor(mc, 32, 64));
            const float mnew = fmaxf(m, mc);
            const float al = __builtin_amdgcn_exp2f(m - mnew);
            float ls = 0.0f;
#pragma unroll
            for (int i = 0; i < 16; ++i) {
                sv[i] = __builtin_amdgcn_exp2f(sv[i] - mnew);
                ls += sv[i];
            }
            ls += __shfl_xor(ls, 16, 64);
            ls += __shfl_xor(ls, 32, 64);
            lsum = lsum * al + ls;
            m = mnew;
#pragma unroll
            for (int dblk = 0; dblk < 8; ++dblk) o[dblk] *= al;

            bf16* pw = &Ps[wave * 1024 + l15 * 64];
#pragma unroll
            for (int kblk = 0; kblk < 4; ++kblk) {
                bf16x4 pb = {(bf16)sv[kblk * 4 + 0], (bf16)sv[kblk * 4 + 1],
                             (bf16)sv[kblk * 4 + 2], (bf16)sv[kblk * 4 + 3]};
                const int phys = (kblk * 2 + (quad >> 1)) ^ swz;
                *(bf16x4*)&pw[phys * 8 + (quad & 1) * 4] = pb;
            }
#pragma unroll
            for (int kc = 0; kc < 2; ++kc) {
                const int up = ((kc * 4 + quad) ^ swz) * 8;
                bf16x8 pfv = *(const bf16x8*)&pw[up];
#pragma unroll
                for (int dblk = 0; dblk < 8; ++dblk) {
                    bf16x8 vf = *(const bf16x8*)&Vs[(dblk * 16 + l15) * 64 + up];
                    o[dblk] = __builtin_amdgcn_mfma_f32_16x16x32_bf16(vf, pfv, o[dblk], 0, 0, 0);
                }
            }
        }
        __syncthreads();
    }

    const float inv = 1.0f / lsum;
    const int q = qw0 + l15;
    bf16* ob = Out + (size_t)(b * S_ + q) * HD_ + h * 128;
#pragma unroll
    for (int dblk = 0; dblk < 8; ++dblk) {
        bf16x4 ov = {(bf16)(o[dblk][0] * inv), (bf16)(o[dblk][1] * inv),
                     (bf16)(o[dblk][2] * inv), (bf16)(o[dblk][3] * inv)};
        *(bf16x4*)&ob[dblk * 16 + quad * 4] = ov;
    }
}

// ---------------- launch ----------------
extern "C" void kernel_launch(void* const* d_in, const int* in_sizes, int n_in, void* d_out,
                              int out_size, void* d_ws, size_t ws_size, hipStream_t stream) {
    const float* x = (const float*)d_in[0];
    const float* cosp = (const float*)d_in[1];
    const float* sinp = (const float*)d_in[2];
    const float* Wq = (const float*)d_in[3];
    const float* Wk = (const float*)d_in[4];
    const float* Wv = (const float*)d_in[5];
    const float* Wo = (const float*)d_in[6];
    float* out = (float*)d_out;

    constexpr size_t MB = 1ull << 20;
    char* ws = (char*)d_ws;
    bf16* xb    = (bf16*)(ws + 0);          // x bf16 (4096x2048)        16 MB
    bf16* wqkv  = (bf16*)(ws + 16 * MB);    // Wq|Wk|Wv bf16 (3072x2048) 12 MB
    bf16* wo    = (bf16*)(ws + 28 * MB);    // Wo bf16 (2048x2048)        8 MB
    bf16* qn    = (bf16*)(ws + 40 * MB);    // (B,H,S,D)                 16 MB
    bf16* kn    = (bf16*)(ws + 56 * MB);    // (B,KV,S,D)                 4 MB
    bf16* vt    = (bf16*)(ws + 60 * MB);    // (B,KV,D,S)                 4 MB
    bf16* attnb = (bf16*)(ws + 64 * MB);    // (B,S,H*D)                 16 MB

    // one fused cvt writes xb, wqkv, wo back-to-back (contiguous dst)
    cvt_all<<<18432, 256, 0, stream>>>(x, Wq, Wk, Wv, Wo, xb);
    gemm_qkv_rope<<<dim3(32, 24), 256, 0, stream>>>(xb, wqkv, cosp, sinp, qn, kn, vt);
    attn_fwd<<<dim3(32, 16, 2), 256, 0, stream>>>(qn, kn, vt, attnb);
    gemm_bt<float><<<dim3(32, 16), 256, 0, stream>>>(attnb, wo, out, 2048, 2048);
}

// Round 6
// 295.743 us; speedup vs baseline: 1.4665x; 1.0498x over previous
//
#include <hip/hip_runtime.h>
#include <stdint.h>

using bf16 = __bf16;
typedef __bf16 bf16x8 __attribute__((ext_vector_type(8)));
typedef __bf16 bf16x4 __attribute__((ext_vector_type(4)));
typedef float f32x4 __attribute__((ext_vector_type(4)));

#define H_ 16
#define KV_ 4
#define D_ 128
#define WIN_ 1024
#define B_ 2
#define S_ 2048
#define E_ 2048
#define HD_ 2048

// async global->LDS, 16B per lane. LDS dest must be wave-uniform base + lane*16.
__device__ __forceinline__ void gld_lds16(const void* gptr, void* lptr) {
    __builtin_amdgcn_global_load_lds(
        (__attribute__((address_space(1))) void*)(uintptr_t)gptr,
        (__attribute__((address_space(3))) void*)(uintptr_t)lptr, 16, 0, 0);
}

// ---------------- fused fp32 -> bf16 conversion (x, Wq, Wk, Wv, Wo -> one contiguous dst) ----
__global__ __launch_bounds__(256) void cvt_all(const float* __restrict__ x,
                                               const float* __restrict__ wq,
                                               const float* __restrict__ wk,
                                               const float* __restrict__ wv,
                                               const float* __restrict__ wo,
                                               bf16* __restrict__ dst) {
    int i = (blockIdx.x * 256 + threadIdx.x) * 4;  // into 18,874,368-elem concatenation
    const float* src;
    int off;
    if (i < 8388608)       { src = x;  off = 0; }
    else if (i < 12582912) { src = wq; off = 8388608; }
    else if (i < 13631488) { src = wk; off = 12582912; }
    else if (i < 14680064) { src = wv; off = 13631488; }
    else                   { src = wo; off = 14680064; }
    const float4 v = *(const float4*)(src + (i - off));
    bf16x4 o = {(bf16)v.x, (bf16)v.y, (bf16)v.z, (bf16)v.w};
    *(bf16x4*)(dst + i) = o;
}

// BK=64 swizzle scheme: LDS row = 64 bf16 = 128 B (full bank wrap), 8 x 16B units/row.
// Physical unit p of row r holds logical unit p ^ (r&7). Staging: thread t stages
// row t>>3, phys unit t&7 -> source unit (t&7)^((t>>3)&7). Fragment (k-half kh):
// phys unit = (kh*4+quad) ^ (l15&7) -> 2 lanes/unit (2-way, free).

// ---------------- GEMM: C[m,n] = sum_k A[m,k] * W[n,k] (plain epilogue; out-proj) ----------
template <typename OutT>
__global__ __launch_bounds__(256) void gemm_bt(const bf16* __restrict__ A,
                                               const bf16* __restrict__ W,
                                               OutT* __restrict__ C, int K, int ldc) {
    __shared__ alignas(16) bf16 As[128 * 64];
    __shared__ alignas(16) bf16 Bs[128 * 64];
    const int t = threadIdx.x;
    const int lane = t & 63;
    const int wave = t >> 6;
    const int l15 = lane & 15;
    const int quad = lane >> 4;
    const int fsw = l15 & 7;  // fragment-read swizzle
    const int wm = (wave & 1) * 64;
    const int wn = (wave >> 1) * 64;
    const int m0 = blockIdx.x * 128;
    const int n0 = blockIdx.y * 128;

    f32x4 acc[4][4] = {};

    const int sr = t >> 3;                              // 0..31
    const int su = ((t & 7) ^ ((t >> 3) & 7)) * 8;      // swizzled source unit
    const bf16* Ap = A + (size_t)(m0 + sr) * K + su;
    const bf16* Wp = W + (size_t)(n0 + sr) * K + su;

    for (int k0 = 0; k0 < K; k0 += 64) {
#pragma unroll
        for (int c = 0; c < 4; ++c) {
            gld_lds16(Ap + k0 + (size_t)c * 32 * K, &As[c * 2048 + t * 8]);
            gld_lds16(Wp + k0 + (size_t)c * 32 * K, &Bs[c * 2048 + t * 8]);
        }
        __syncthreads();
#pragma unroll
        for (int kh = 0; kh < 2; ++kh) {
            bf16x8 af[4], bfr[4];
#pragma unroll
            for (int i = 0; i < 4; ++i) {
                af[i] = *(const bf16x8*)&As[(wm + i * 16 + l15) * 64 +
                                            (((kh * 4 + quad) ^ fsw) * 8)];
                bfr[i] = *(const bf16x8*)&Bs[(wn + i * 16 + l15) * 64 +
                                             (((kh * 4 + quad) ^ fsw) * 8)];
            }
#pragma unroll
            for (int i = 0; i < 4; ++i)
#pragma unroll
                for (int j = 0; j < 4; ++j)
                    acc[i][j] =
                        __builtin_amdgcn_mfma_f32_16x16x32_bf16(af[i], bfr[j], acc[i][j], 0, 0, 0);
        }
        __syncthreads();
    }
#pragma unroll
    for (int i = 0; i < 4; ++i) {
        const int row = m0 + wm + i * 16 + quad * 4;
#pragma unroll
        for (int j = 0; j < 4; ++j) {
            const int col = n0 + wn + j * 16 + l15;
#pragma unroll
            for (int r = 0; r < 4; ++r) C[(size_t)(row + r) * ldc + col] = (OutT)acc[i][j][r];
        }
    }
}

// ---------------- QKV GEMM with fused RoPE + RMSNorm + V-transpose epilogue ----------------
// grid.y = 24 units: 0..15 q heads, 16..19 k heads, 20..23 v heads. Each N-tile of 128
// is exactly one head, so the block owns the full normalization group.
// LDS: Cs (post-loop) ALIASES As/Bs (K-loop) -> 34,816 B total.
__global__ __launch_bounds__(256) void gemm_qkv_rope(const bf16* __restrict__ A,
                                                     const bf16* __restrict__ W,
                                                     const float* __restrict__ cosp,
                                                     const float* __restrict__ sinp,
                                                     bf16* __restrict__ qn,
                                                     bf16* __restrict__ kn,
                                                     bf16* __restrict__ vt) {
    __shared__ alignas(16) unsigned char smem[128 * 136 * 2];  // 34,816 B union
    bf16* As = (bf16*)smem;                  // 128*64 = 16 KB  (K-loop)
    bf16* Bs = (bf16*)(smem + 16384);        // 128*64 = 16 KB  (K-loop)
    bf16* Cs = (bf16*)smem;                  // 128*136 = 34 KB (epilogue, aliases As/Bs)
    const int t = threadIdx.x;
    const int lane = t & 63;
    const int wave = t >> 6;
    const int l15 = lane & 15;
    const int quad = lane >> 4;
    const int fsw = l15 & 7;
    const int wm = (wave & 1) * 64;
    const int wn = (wave >> 1) * 64;
    const int m0 = blockIdx.x * 128;
    const int n0 = blockIdx.y * 128;
    const int K = E_;

    f32x4 acc[4][4] = {};

    const int sr = t >> 3;
    const int su = ((t & 7) ^ ((t >> 3) & 7)) * 8;
    const bf16* Ap = A + (size_t)(m0 + sr) * K + su;
    const bf16* Wp = W + (size_t)(n0 + sr) * K + su;

    for (int k0 = 0; k0 < K; k0 += 64) {
#pragma unroll
        for (int c = 0; c < 4; ++c) {
            gld_lds16(Ap + k0 + (size_t)c * 32 * K, &As[c * 2048 + t * 8]);
            gld_lds16(Wp + k0 + (size_t)c * 32 * K, &Bs[c * 2048 + t * 8]);
        }
        __syncthreads();
#pragma unroll
        for (int kh = 0; kh < 2; ++kh) {
            bf16x8 af[4], bfr[4];
#pragma unroll
            for (int i = 0; i < 4; ++i) {
                af[i] = *(const bf16x8*)&As[(wm + i * 16 + l15) * 64 +
                                            (((kh * 4 + quad) ^ fsw) * 8)];
                bfr[i] = *(const bf16x8*)&Bs[(wn + i * 16 + l15) * 64 +
                                             (((kh * 4 + quad) ^ fsw) * 8)];
            }
#pragma unroll
            for (int i = 0; i < 4; ++i)
#pragma unroll
                for (int j = 0; j < 4; ++j)
                    acc[i][j] =
                        __builtin_amdgcn_mfma_f32_16x16x32_bf16(af[i], bfr[j], acc[i][j], 0, 0, 0);
        }
        __syncthreads();
    }
    // after the loop-end barrier all ds_reads are drained -> safe to reuse As/Bs as Cs

    // stash tile to LDS (bf16, same rounding the old qkv global buffer had)
#pragma unroll
    for (int i = 0; i < 4; ++i) {
        const int row = wm + i * 16 + quad * 4;
#pragma unroll
        for (int j = 0; j < 4; ++j) {
            const int col = wn + j * 16 + l15;
#pragma unroll
            for (int r = 0; r < 4; ++r) Cs[(row + r) * 136 + col] = (bf16)acc[i][j][r];
        }
    }
    __syncthreads();

    const int unit = n0 >> 7;  // == blockIdx.y
    if (unit < 20) {
        // 2 threads per token row; each handles d = half*32 .. half*32+31
        const int row = t >> 1;
        const int half = t & 1;
        const int gr = m0 + row;
        const int bb = gr >> 11;
        const int s = gr & 2047;
        const bf16* crow = &Cs[row * 136 + half * 32];
        const float* cp = cosp + s * 64 + half * 32;
        const float* sp = sinp + s * 64 + half * 32;
        bf16x8 xa[4], xb2[4];
#pragma unroll
        for (int u = 0; u < 4; ++u) {
            xa[u] = *(const bf16x8*)(crow + u * 8);
            xb2[u] = *(const bf16x8*)(crow + 64 + u * 8);
        }
        float y1[32], y2[32], ss = 0.0f;
#pragma unroll
        for (int u = 0; u < 4; ++u)
#pragma unroll
            for (int e = 0; e < 8; ++e) {
                const int jj = u * 8 + e;
                const float x1 = (float)xa[u][e];
                const float x2 = (float)xb2[u][e];
                const float c = cp[jj];
                const float sn = sp[jj];
                y1[jj] = x1 * c + x2 * sn;
                y2[jj] = x2 * c - x1 * sn;
                ss += y1[jj] * y1[jj] + y2[jj] * y2[jj];
            }
        ss += __shfl_xor(ss, 1, 64);
        float rr = rsqrtf(ss * (1.0f / 128.0f) + 1.1920929e-7f);
        bf16* dst;
        if (unit < 16) {
            rr *= 0.12751740f;  // D^-0.5 * log2(e): exp2-domain softmax in attn
            dst = qn + ((size_t)(bb * H_ + unit) * S_ + s) * 128 + half * 32;
        } else {
            dst = kn + ((size_t)(bb * KV_ + (unit - 16)) * S_ + s) * 128 + half * 32;
        }
#pragma unroll
        for (int u = 0; u < 4; ++u) {
            bf16x8 p1, p2;
#pragma unroll
            for (int e = 0; e < 8; ++e) {
                p1[e] = (bf16)(y1[u * 8 + e] * rr);
                p2[e] = (bf16)(y2[u * 8 + e] * rr);
            }
            *(bf16x8*)(dst + u * 8) = p1;
            *(bf16x8*)(dst + 64 + u * 8) = p2;
        }
    } else {
        // V: transpose tile -> vt[(b,jv,d,s)], thread owns one d, 64 s-positions
        const int jv = unit - 20;
        const int d = t >> 1;
        const int sl0 = (t & 1) * 64;
        const int s0 = (m0 & 2047) + sl0;
        const int bb = m0 >> 11;
        bf16* vdst = vt + ((size_t)(bb * KV_ + jv) * 128 + d) * S_ + s0;
#pragma unroll
        for (int u = 0; u < 8; ++u) {
            bf16x8 pk;
#pragma unroll
            for (int e = 0; e < 8; ++e) pk[e] = Cs[(sl0 + u * 8 + e) * 136 + d];
            *(bf16x8*)(vdst + u * 8) = pk;
        }
    }
}

// ---------------- flash attention, sliding window, S^T orientation ----------------
__global__ __launch_bounds__(256, 4) void attn_fwd(const bf16* __restrict__ Qn,
                                                   const bf16* __restrict__ Kn,
                                                   const bf16* __restrict__ Vt,
                                                   bf16* __restrict__ Out) {
    __shared__ alignas(16) bf16 Ks[64 * 128];
    __shared__ alignas(16) bf16 Vs[128 * 64];
    __shared__ alignas(16) bf16 Ps[4 * 16 * 64];

    const int t = threadIdx.x;
    const int lane = t & 63;
    const int wave = t >> 6;
    const int l15 = lane & 15;
    const int quad = lane >> 4;
    const int swz = l15 & 7;
    const int qb0 = blockIdx.x * 64;
    const int h = blockIdx.y;
    const int b = blockIdx.z;
    const int hk = h >> 2;
    const int qw0 = qb0 + wave * 16;

    const bf16* qbase = Qn + ((size_t)((b * H_ + h) * S_) + qw0 + l15) * 128;
    bf16x8 qf[4];
#pragma unroll
    for (int c4 = 0; c4 < 4; ++c4) qf[c4] = *(const bf16x8*)(qbase + c4 * 32 + quad * 8);

    f32x4 o[8] = {};
    float m = -1e30f, lsum = 0.0f;

    const bf16* kroot = Kn + (size_t)((b * KV_ + hk) * S_) * 128;
    const bf16* vroot = Vt + (size_t)((b * KV_ + hk) * 128) * S_;

    const int ku = (t & 15) ^ ((t >> 4) & 7);
    const int krow = t >> 4;
    const int vu = (t & 7) ^ ((t >> 3) & 7);
    const int vrow = t >> 3;
    const bf16* kst = kroot + (size_t)krow * 128 + ku * 8;
    const bf16* vst = vroot + (size_t)vrow * S_ + vu * 8;
    bf16* ksl = &Ks[t * 8];
    bf16* vsl = &Vs[t * 8];

    int lo = qb0 - (WIN_ - 1);
    if (lo < 0) lo = 0;
    const int kb_start = lo & ~63;
    const int kb_end = qb0 + 64;

    for (int kb = kb_start; kb < kb_end; kb += 64) {
#pragma unroll
        for (int c = 0; c < 4; ++c) gld_lds16(kst + (size_t)(kb + c * 16) * 128, ksl + c * 2048);
#pragma unroll
        for (int c = 0; c < 4; ++c) gld_lds16(vst + (size_t)(c * 32) * S_ + kb, vsl + c * 2048);
        __syncthreads();

        const bool wave_active = (kb + 63 >= qw0 - (WIN_ - 1));
        if (wave_active) {
            f32x4 sacc[4] = {};
#pragma unroll
            for (int kblk = 0; kblk < 4; ++kblk)
#pragma unroll
                for (int c4 = 0; c4 < 4; ++c4) {
                    bf16x8 kf = *(const bf16x8*)&Ks[(kblk * 16 + l15) * 128 +
                                                    (((c4 * 4 + quad) ^ swz) * 8)];
                    sacc[kblk] =
                        __builtin_amdgcn_mfma_f32_16x16x32_bf16(kf, qf[c4], sacc[kblk], 0, 0, 0);
                }

            const int q = qw0 + l15;
            float sv[16];
            const bool interior = (kb + 63 <= qw0) && (kb >= qw0 + 15 - (WIN_ - 1));
            if (interior) {
#pragma unroll
                for (int kblk = 0; kblk < 4; ++kblk)
#pragma unroll
                    for (int r = 0; r < 4; ++r) sv[kblk * 4 + r] = sacc[kblk][r];
            } else {
#pragma unroll
                for (int kblk = 0; kblk < 4; ++kblk)
#pragma unroll
                    for (int r = 0; r < 4; ++r) {
                        const int key = kb + kblk * 16 + quad * 4 + r;
                        const bool valid = (key <= q) && (q - key < WIN_);
                        sv[kblk * 4 + r] = valid ? sacc[kblk][r] : -1e30f;
                    }
            }
            float mc = sv[0];
#pragma unroll
            for (int i = 1; i < 16; ++i) mc = fmaxf(mc, sv[i]);
            mc = fmaxf(mc, __shfl_xor(mc, 16, 64));
            mc = fmaxf(mc, __shfl_xor(mc, 32, 64));
            const float mnew = fmaxf(m, mc);
            const float al = __builtin_amdgcn_exp2f(m - mnew);
            float ls = 0.0f;
#pragma unroll
            for (int i = 0; i < 16; ++i) {
                sv[i] = __builtin_amdgcn_exp2f(sv[i] - mnew);
                ls += sv[i];
            }
            ls += __shfl_xor(ls, 16, 64);
            ls += __shfl_xor(ls, 32, 64);
            lsum = lsum * al + ls;
            m = mnew;
#pragma unroll
            for (int dblk = 0; dblk < 8; ++dblk) o[dblk] *= al;

            bf16* pw = &Ps[wave * 1024 + l15 * 64];
#pragma unroll
            for (int kblk = 0; kblk < 4; ++kblk) {
                bf16x4 pb = {(bf16)sv[kblk * 4 + 0], (bf16)sv[kblk * 4 + 1],
                             (bf16)sv[kblk * 4 + 2], (bf16)sv[kblk * 4 + 3]};
                const int phys = (kblk * 2 + (quad >> 1)) ^ swz;
                *(bf16x4*)&pw[phys * 8 + (quad & 1) * 4] = pb;
            }
#pragma unroll
            for (int kc = 0; kc < 2; ++kc) {
                const int up = ((kc * 4 + quad) ^ swz) * 8;
                bf16x8 pfv = *(const bf16x8*)&pw[up];
#pragma unroll
                for (int dblk = 0; dblk < 8; ++dblk) {
                    bf16x8 vf = *(const bf16x8*)&Vs[(dblk * 16 + l15) * 64 + up];
                    o[dblk] = __builtin_amdgcn_mfma_f32_16x16x32_bf16(vf, pfv, o[dblk], 0, 0, 0);
                }
            }
        }
        __syncthreads();
    }

    const float inv = 1.0f / lsum;
    const int q = qw0 + l15;
    bf16* ob = Out + (size_t)(b * S_ + q) * HD_ + h * 128;
#pragma unroll
    for (int dblk = 0; dblk < 8; ++dblk) {
        bf16x4 ov = {(bf16)(o[dblk][0] * inv), (bf16)(o[dblk][1] * inv),
                     (bf16)(o[dblk][2] * inv), (bf16)(o[dblk][3] * inv)};
        *(bf16x4*)&ob[dblk * 16 + quad * 4] = ov;
    }
}

// ---------------- launch ----------------
extern "C" void kernel_launch(void* const* d_in, const int* in_sizes, int n_in, void* d_out,
                              int out_size, void* d_ws, size_t ws_size, hipStream_t stream) {
    const float* x = (const float*)d_in[0];
    const float* cosp = (const float*)d_in[1];
    const float* sinp = (const float*)d_in[2];
    const float* Wq = (const float*)d_in[3];
    const float* Wk = (const float*)d_in[4];
    const float* Wv = (const float*)d_in[5];
    const float* Wo = (const float*)d_in[6];
    float* out = (float*)d_out;

    constexpr size_t MB = 1ull << 20;
    char* ws = (char*)d_ws;
    bf16* xb    = (bf16*)(ws + 0);          // x bf16 (4096x2048)        16 MB
    bf16* wqkv  = (bf16*)(ws + 16 * MB);    // Wq|Wk|Wv bf16 (3072x2048) 12 MB
    bf16* wo    = (bf16*)(ws + 28 * MB);    // Wo bf16 (2048x2048)        8 MB
    bf16* qn    = (bf16*)(ws + 40 * MB);    // (B,H,S,D)                 16 MB
    bf16* kn    = (bf16*)(ws + 56 * MB);    // (B,KV,S,D)                 4 MB
    bf16* vt    = (bf16*)(ws + 60 * MB);    // (B,KV,D,S)                 4 MB
    bf16* attnb = (bf16*)(ws + 64 * MB);    // (B,S,H*D)                 16 MB

    // one fused cvt writes xb, wqkv, wo back-to-back (contiguous dst)
    cvt_all<<<18432, 256, 0, stream>>>(x, Wq, Wk, Wv, Wo, xb);
    gemm_qkv_rope<<<dim3(32, 24), 256, 0, stream>>>(xb, wqkv, cosp, sinp, qn, kn, vt);
    attn_fwd<<<dim3(32, 16, 2), 256, 0, stream>>>(qn, kn, vt, attnb);
    gemm_bt<float><<<dim3(32, 16), 256, 0, stream>>>(attnb, wo, out, 2048, 2048);
}